// Round 3
// baseline (577.423 us; speedup 1.0000x reference)
//
#include <hip/hip_runtime.h>

#define TT 128
#define BB 32
#define II 128
#define HH 320
#define OO 32
#define GG 8
#define HPAD 129   // s_hist row pitch (pad: rows are read down-column in final rewrite)

static __device__ __forceinline__ float fexp2(float x) { return __builtin_amdgcn_exp2f(x); }
static __device__ __forceinline__ float frcp(float x)  { return __builtin_amdgcn_rcpf(x); }

// tanh for x >= 0: 1 - 2/(e^{2x}+1), e^{2x} = exp2(x * 2*log2(e))
static __device__ __forceinline__ float tanh_pos(float x) {
    float e = fexp2(x * 2.8853900817779268f);
    return 1.0f - 2.0f * frcp(e + 1.0f);
}

__global__ __launch_bounds__(512, 2)
void leaky_rnn_kernel(const float* __restrict__ x, const float* __restrict__ Rs,
                      const float* __restrict__ Wx2h, const float* __restrict__ Wh2h,
                      const float* __restrict__ bh2h, const float* __restrict__ Wh2o,
                      const float* __restrict__ bh2o, const float* __restrict__ Wattn,
                      const float* __restrict__ battn, const float* __restrict__ cplas,
                      float* __restrict__ out, float* __restrict__ hs,
                      unsigned* __restrict__ ctr)
{
    const int tid  = threadIdx.x;
    const int bid  = blockIdx.x;
    const int b    = bid >> 3;     // batch  (round-0 proven mapping)
    const int sub  = bid & 7;      // 8 blocks per batch, 40 rows each
    const int w    = tid >> 6;     // wave 0..7
    const int lane = tid & 63;
    const int h0   = sub * 40;

    __shared__ float s_hist[40 * HPAD];  // this block's 40 rows x 128 t (true values)
    __shared__ float s_hs[16 * HH];      // readout staging (final phase only)

    // ---- per-thread register copies of everything the wave needs ----
    // attention weights: this lane's 5 column-slices of all 8 groups
    float ea_r[8][5], ba[8];
#pragma unroll
    for (int g = 0; g < 8; ++g) {
        ba[g] = battn[g];
#pragma unroll
        for (int k = 0; k < 5; ++k) {
            int j = lane + 64 * k;
            float m = (j < 256) ? 1.f : (j == 256 ? -1.f : 0.f);  // mask_a (zc=63!)
            ea_r[g][k] = fmaxf(Wattn[g * HH + j], 0.f) * m;
        }
    }

    // plastic weights in registers: 5 rows/wave, lane owns cols {lane, lane+64,...}
    float wx[5][2], wh[5][5], st[5], bh[5];
    int hrow[5];
#pragma unroll
    for (int r = 0; r < 5; ++r) {
        int h = h0 + w * 5 + r;
        hrow[r] = h;
        bh[r] = bh2h[h];
        st[r] = 0.f;
#pragma unroll
        for (int c = 0; c < 2; ++c)
            wx[r][c] = fmaxf(Wx2h[h * II + lane + 64 * c], 0.f);   // wx0 = relu(W_x2h)
#pragma unroll
        for (int c = 0; c < 5; ++c) {
            int j = lane + 64 * c;
            float v = fmaxf(Wh2h[h * HH + j], 0.f);
            v = (c == 4) ? -v : v;            // sign_h: j>=256 -> -1
            wh[r][c] = (j == h) ? 0.f : v;    // zero diagonal (1-eye)
        }
    }
    float c0 = fabsf(cplas[0]), c1 = fabsf(cplas[1]), c2 = fabsf(cplas[2]);
    float c3 = fabsf(cplas[3]), c4 = fabsf(cplas[4]), c5 = fabsf(cplas[5]);

    const float AX  = (float)(0.02 / 0.1);   // 0.2
    const float AW  = (float)(0.02 / 0.2);   // 0.1
    const float OMX = 1.f - AX;
    const float OMW = 1.f - AW;
    const float L2E = 1.4426950408889634f;

    // prev-output column slice (this lane's 5 values); output0 = relu(0) = 0
    float oc[5] = {0.f, 0.f, 0.f, 0.f, 0.f};

    // prefetch x (both halves) and Rs for t=0
    float xv0n = x[b * II + lane];
    float xv1n = x[b * II + lane + 64];
    float Rvn  = Rs[b];

    // ================= free-running t-loop: NO intra-loop barriers =========
    // Each wave is autonomous: it computes all 8 attention logits itself
    // (bit-identical chain+butterfly to the staged version), consumes only
    // its own 5-per-lane slice of the hidden state, and polls that slice
    // directly from hs (data-is-flag, biased +2). Waves may drift in t --
    // the protocol is per-(t,h) slot, so no ordering assumptions.
#pragma unroll 1
    for (int t = 0; t < TT; ++t) {
        float xv0 = xv0n, xv1 = xv1n;
        float A   = AW * Rvn;

        // ---- all 8 attention logits, redundantly per wave ----
        float lg[8];
#pragma unroll
        for (int g = 0; g < 8; ++g) {
            float lp = 0.f;
#pragma unroll
            for (int k = 0; k < 5; ++k)
                lp = fmaf(ea_r[g][k], oc[k], lp);
            lg[g] = lp;
        }
#pragma unroll
        for (int m = 1; m < 64; m <<= 1) {
#pragma unroll
            for (int g = 0; g < 8; ++g) lg[g] += __shfl_xor(lg[g], m, 64);
        }
#pragma unroll
        for (int g = 0; g < 8; ++g) lg[g] += ba[g];

        // ---- softmax (identical op order to previous version) ----
        float mx = lg[0];
#pragma unroll
        for (int g = 1; g < 8; ++g) mx = fmaxf(mx, lg[g]);
        float se = 0.f, eg[8];
#pragma unroll
        for (int g = 0; g < 8; ++g) { eg[g] = fexp2((lg[g] - mx) * L2E); se += eg[g]; }
        float rinv = frcp(se);
        float xmc0 = xv0 * eg[lane >> 4] * 8.f * rinv;
        float xmc1 = xv1 * eg[(lane >> 4) + 4] * 8.f * rinv;

        // ---- 5 row-dot partials, ILP-interleaved butterfly ----
        float p[5];
#pragma unroll
        for (int r = 0; r < 5; ++r) {
            int h = hrow[r];
            float pp = fmaxf(wx[r][0], 0.f) * xmc0;
            pp = fmaf(fmaxf(wx[r][1], 0.f), xmc1, pp);
#pragma unroll
            for (int c = 0; c < 5; ++c) {
                float wv = fmaxf(wh[r][c], 0.f);
                float so = (c == 4) ? -oc[4] : oc[c];        // sign_h fold
                float term = wv * so;
                term = ((lane + 64 * c) == h) ? 0.f : term;  // exclude diagonal
                pp += term;
            }
            p[r] = pp;
        }
#pragma unroll
        for (int m = 1; m < 64; m <<= 1) {
#pragma unroll
            for (int r = 0; r < 5; ++r) p[r] += __shfl_xor(p[r], m, 64);
        }

        float no[5];
#pragma unroll
        for (int r = 0; r < 5; ++r) {
            float total = p[r] + bh[r];
            st[r] = fmaf(st[r], OMX, total * AX);
            no[r] = tanh_pos(fmaxf(st[r], 0.f));
        }

        // ---- batched publish: lanes 0..4 store 5 consecutive h (one line).
        //      Biased (+2): poison 0xAA.. and memset-0 are < 1. ----
        {
            float pub = no[0];
            pub = (lane == 1) ? no[1] : pub;
            pub = (lane == 2) ? no[2] : pub;
            pub = (lane == 3) ? no[3] : pub;
            pub = (lane == 4) ? no[4] : pub;
            if (lane < 5) {
                __hip_atomic_store(&hs[(t * BB + b) * HH + h0 + w * 5 + lane], pub + 2.0f,
                                   __ATOMIC_RELAXED, __HIP_MEMORY_SCOPE_AGENT);
                s_hist[(w * 5 + lane) * HPAD + t] = pub;   // true value for final rewrite
            }
        }

        // ---- plastic weight update (regs only; overlaps store propagation) ----
        if (t < TT - 1) {
            float Ac0 = A * c0, Ac1 = A * c1, Ac2 = A * c2;
            float Ac3 = A * c3, Ac4 = A * c4, Ac5 = A * c5;
#pragma unroll
            for (int r = 0; r < 5; ++r) {
                float u  = fmaf(Ac2, no[r], Ac0);
                float v  = Ac1 * no[r];
                float pp = fmaf(Ac5, no[r], Ac3);
                float qq = Ac4 * no[r];
                wx[r][0] = fmaf(wx[r][0], OMW, fmaf(u, xmc0, v));
                wx[r][1] = fmaf(wx[r][1], OMW, fmaf(u, xmc1, v));
#pragma unroll
                for (int c = 0; c < 5; ++c)
                    wh[r][c] = fmaf(wh[r][c], OMW, fmaf(pp, oc[c], qq));
            }
        }

        // prefetch next x/R while publish stores are in flight
        if (t + 1 < TT) {
            xv0n = x[((t + 1) * BB + b) * II + lane];
            xv1n = x[((t + 1) * BB + b) * II + lane + 64];
            Rvn  = Rs[(t + 1) * BB + b];
        }

        // ---- poll this lane's 5 next-step values straight into registers
        //      (no LDS, no barrier). Reload-all spin: each iteration is one
        //      RTT with 5 loads in flight. ----
        if (t < TT - 1) {
            const float* base = &hs[(t * BB + b) * HH + lane];
            float v0, v1, v2, v3, v4;
            int guard = 0;
            do {
                v0 = __hip_atomic_load(base,       __ATOMIC_RELAXED, __HIP_MEMORY_SCOPE_AGENT);
                v1 = __hip_atomic_load(base + 64,  __ATOMIC_RELAXED, __HIP_MEMORY_SCOPE_AGENT);
                v2 = __hip_atomic_load(base + 128, __ATOMIC_RELAXED, __HIP_MEMORY_SCOPE_AGENT);
                v3 = __hip_atomic_load(base + 192, __ATOMIC_RELAXED, __HIP_MEMORY_SCOPE_AGENT);
                v4 = __hip_atomic_load(base + 256, __ATOMIC_RELAXED, __HIP_MEMORY_SCOPE_AGENT);
                float mn = fminf(fminf(fminf(v0, v1), fminf(v2, v3)), v4);
                if (mn >= 1.0f) break;
            } while (++guard < 2000000);   // failsafe: never hang
            oc[0] = v0 - 2.0f; oc[1] = v1 - 2.0f; oc[2] = v2 - 2.0f;
            oc[3] = v3 - 2.0f; oc[4] = v4 - 2.0f;
        }
    }

    // ======== final phase (proven round-0/2 structure, unchanged) ========
    __syncthreads();   // join the block's free-running waves

    // Barrier A among the 8 sibling blocks: everyone's t-loop done, all hs published.
    if (tid == 0) {
        __hip_atomic_fetch_add(&ctr[b * 32], 1u, __ATOMIC_RELAXED, __HIP_MEMORY_SCOPE_AGENT);
        int guard = 0;
        while (__hip_atomic_load(&ctr[b * 32], __ATOMIC_RELAXED, __HIP_MEMORY_SCOPE_AGENT) < 8u) {
            if (++guard > 2000000) break;
            __builtin_amdgcn_s_sleep(1);
        }
    }
    __syncthreads();

    // readout staging: load biased hs, subtract bias
    for (int idx = tid; idx < 16 * HH; idx += 512) {
        int tl = idx / HH, h = idx % HH;
        int t_g = sub * 16 + tl;
        s_hs[idx] = __hip_atomic_load(&hs[(t_g * BB + b) * HH + h],
                                      __ATOMIC_RELAXED, __HIP_MEMORY_SCOPE_AGENT) - 2.0f;
    }
    __syncthreads();
    {
        int t_loc = tid >> 5;          // 0..15
        int o     = tid & 31;
        int t_g   = sub * 16 + t_loc;
        const float* hp = &s_hs[t_loc * HH];
        float acc = bh2o[o];
#pragma unroll 4
        for (int h = 0; h < 257; ++h) {          // mask_o zero for h>256
            float m = (h == 256) ? -1.f : 1.f;   // h==256: sign -1, exist 1 (zc=63)
            acc = fmaf(fmaxf(Wh2o[o * HH + h], 0.f) * m, hp[h], acc);
        }
        float sg = frcp(1.f + fexp2(-acc * L2E));
        out[(t_g * BB + b) * OO + o] = sg;
    }

    // Barrier B: all siblings finished READING biased hs -> safe to rewrite
    __syncthreads();
    if (tid == 0) {
        __hip_atomic_fetch_add(&ctr[b * 32], 1u, __ATOMIC_RELAXED, __HIP_MEMORY_SCOPE_AGENT);
        int guard = 0;
        while (__hip_atomic_load(&ctr[b * 32], __ATOMIC_RELAXED, __HIP_MEMORY_SCOPE_AGENT) < 16u) {
            if (++guard > 2000000) break;
            __builtin_amdgcn_s_sleep(1);
        }
    }
    __syncthreads();

    // rewrite own rows of hs with TRUE values (word-granular agent stores:
    // no cross-XCD partial-dirty-line merge concerns)
    for (int idx = tid; idx < 40 * TT; idx += 512) {
        int row = idx >> 7;            // idx / 128
        int t   = idx & 127;
        __hip_atomic_store(&hs[(t * BB + b) * HH + h0 + row], s_hist[row * HPAD + t],
                           __ATOMIC_RELAXED, __HIP_MEMORY_SCOPE_AGENT);
    }
}

extern "C" void kernel_launch(void* const* d_in, const int* in_sizes, int n_in,
                              void* d_out, int out_size, void* d_ws, size_t ws_size,
                              hipStream_t stream) {
    const float* x     = (const float*)d_in[0];
    const float* Rs    = (const float*)d_in[1];
    const float* Wx2h  = (const float*)d_in[2];
    const float* Wh2h  = (const float*)d_in[3];
    const float* bh2h  = (const float*)d_in[4];
    const float* Wh2o  = (const float*)d_in[5];
    const float* bh2o  = (const float*)d_in[6];
    const float* Wattn = (const float*)d_in[7];
    const float* battn = (const float*)d_in[8];
    const float* cplas = (const float*)d_in[9];
    float* out = (float*)d_out;
    float* hs  = out + TT * BB * OO;
    unsigned* ctr = (unsigned*)d_ws;   // 32 counters, 128B apart

    hipMemsetAsync(d_ws, 0, 32 * 32 * sizeof(unsigned), stream);
    hipLaunchKernelGGL(leaky_rnn_kernel, dim3(256), dim3(512), 0, stream,
                       x, Rs, Wx2h, Wh2h, bh2h, Wh2o, bh2o, Wattn, battn, cplas,
                       out, hs, ctr);
}